// Round 1
// baseline (692.418 us; speedup 1.0000x reference)
//
#include <hip/hip_runtime.h>
#include <hip/hip_bf16.h>
#include <stdint.h>

#define HDIM 1024
#define NEXP 8
#define TOPK 2
#define IDIM 1024
#define TWO_I 2048
#define ALPHA 1.702f
#define LIMIT 7.0f
#define EPS 1e-5f

#define BM 128
#define BN 128
#define BK 64

typedef __attribute__((ext_vector_type(8))) short bf16x8;
typedef __attribute__((ext_vector_type(4))) float f32x4;

typedef __attribute__((address_space(1))) const uint32_t g_u32;
typedef __attribute__((address_space(3))) uint32_t l_u32;

__device__ __forceinline__ void load_lds16(const void* g, void* l) {
    // 16B per lane; LDS dest = wave-uniform base + lane*16
    __builtin_amdgcn_global_load_lds((g_u32*)g, (l_u32*)l, 16, 0, 0);
}

__device__ __forceinline__ ushort f2bf(float f) {
    union { float f; uint32_t u; } v{f};
    uint32_t u = v.u;
    return (ushort)((u + 0x7fffu + ((u >> 16) & 1u)) >> 16);  // RNE
}

// ---------------------------------------------------------------------------
// Kernel 1: fp32 -> bf16 convert (weights), grid-stride, float4 vectorized
// ---------------------------------------------------------------------------
__global__ __launch_bounds__(256) void k_f32_to_bf16(const float* __restrict__ src,
                                                     ushort* __restrict__ dst, int n4) {
    int i = blockIdx.x * blockDim.x + threadIdx.x;
    int stride = gridDim.x * blockDim.x;
    for (; i < n4; i += stride) {
        float4 v = reinterpret_cast<const float4*>(src)[i];
        ushort4 o;
        o.x = f2bf(v.x); o.y = f2bf(v.y); o.z = f2bf(v.z); o.w = f2bf(v.w);
        reinterpret_cast<ushort4*>(dst)[i] = o;
    }
}

// ---------------------------------------------------------------------------
// Kernel 2: RMSNorm + router (top-2 softmax) + bucket scatter.
// One block (256 thr) per token. H=1024 -> 4 f32/thread.
// ---------------------------------------------------------------------------
__global__ __launch_bounds__(256) void k_norm_router(
    const float* __restrict__ x, const float* __restrict__ scale,
    const float* __restrict__ gw, const float* __restrict__ gb,
    ushort* __restrict__ t_bf, float* __restrict__ route_w,
    int* __restrict__ counts, int* __restrict__ bucket, int n_tok)
{
    const int n = blockIdx.x;
    const int tid = threadIdx.x;
    const int lane = tid & 63, wid = tid >> 6;

    __shared__ float red[4];
    __shared__ float gred[4][NEXP];

    const float4 xv = reinterpret_cast<const float4*>(x + (size_t)n * HDIM)[tid];
    float ss = xv.x * xv.x + xv.y * xv.y + xv.z * xv.z + xv.w * xv.w;
    #pragma unroll
    for (int off = 32; off; off >>= 1) ss += __shfl_down(ss, off, 64);
    if (lane == 0) red[wid] = ss;
    __syncthreads();
    const float tot = red[0] + red[1] + red[2] + red[3];
    const float rms = rsqrtf(tot / (float)HDIM + EPS);

    const float4 sv = reinterpret_cast<const float4*>(scale)[tid];
    float t0 = xv.x * rms * sv.x;
    float t1 = xv.y * rms * sv.y;
    float t2 = xv.z * rms * sv.z;
    float t3 = xv.w * rms * sv.w;

    ushort4 tb;
    tb.x = f2bf(t0); tb.y = f2bf(t1); tb.z = f2bf(t2); tb.w = f2bf(t3);
    reinterpret_cast<ushort4*>(t_bf + (size_t)n * HDIM)[tid] = tb;

    // gate partials: gw is [H][E], E=8 -> 2 float4 per h
    float g[NEXP];
    #pragma unroll
    for (int e = 0; e < NEXP; ++e) g[e] = 0.f;
    const float tv[4] = {t0, t1, t2, t3};
    const float4* gwv = reinterpret_cast<const float4*>(gw);
    #pragma unroll
    for (int j = 0; j < 4; ++j) {
        const int h = tid * 4 + j;
        const float4 a = gwv[h * 2 + 0];
        const float4 b = gwv[h * 2 + 1];
        g[0] += tv[j] * a.x; g[1] += tv[j] * a.y; g[2] += tv[j] * a.z; g[3] += tv[j] * a.w;
        g[4] += tv[j] * b.x; g[5] += tv[j] * b.y; g[6] += tv[j] * b.z; g[7] += tv[j] * b.w;
    }
    #pragma unroll
    for (int e = 0; e < NEXP; ++e) {
        #pragma unroll
        for (int off = 32; off; off >>= 1) g[e] += __shfl_down(g[e], off, 64);
    }
    if (lane == 0) {
        #pragma unroll
        for (int e = 0; e < NEXP; ++e) gred[wid][e] = g[e];
    }
    __syncthreads();

    if (tid == 0) {
        float gg[NEXP];
        #pragma unroll
        for (int e = 0; e < NEXP; ++e)
            gg[e] = gred[0][e] + gred[1][e] + gred[2][e] + gred[3][e] + gb[e];
        int i0 = 0; float l0 = gg[0];
        #pragma unroll
        for (int e = 1; e < NEXP; ++e) if (gg[e] > l0) { l0 = gg[e]; i0 = e; }
        int i1 = -1; float l1 = -3.4e38f;
        #pragma unroll
        for (int e = 0; e < NEXP; ++e) if (e != i0 && gg[e] > l1) { l1 = gg[e]; i1 = e; }
        const float w0 = 1.f / (1.f + __expf(l1 - l0));
        const float w1 = 1.f - w0;
        route_w[n * 2 + 0] = w0;
        route_w[n * 2 + 1] = w1;
        int p0 = atomicAdd(&counts[i0], 1);
        bucket[i0 * n_tok + p0] = n * 2 + 0;
        int p1 = atomicAdd(&counts[i1], 1);
        bucket[i1 * n_tok + p1] = n * 2 + 1;
    }
}

// ---------------------------------------------------------------------------
// Kernel 3: GEMM1 (gathered rows of t) x W1[e]^T + bias -> SwiGLU -> h1 (bf16)
// C[r][j] = sum_h t[tok(r)][h] * W1[e][j][h].  128x128x64 tile, 4 waves.
// ---------------------------------------------------------------------------
__global__ __launch_bounds__(256) void k_gemm1(
    const ushort* __restrict__ tA, const ushort* __restrict__ w1bf,
    const float* __restrict__ b1,
    const int* __restrict__ counts, const int* __restrict__ bucket,
    ushort* __restrict__ h1, int n_tok, int rt_max)
{
    const int e  = blockIdx.x / rt_max;
    const int rt = blockIdx.x % rt_max;
    const int cnt = counts[e];
    if (rt * BM >= cnt) return;
    const int j0 = blockIdx.y * BN;

    __shared__ __align__(16) ushort As[BM * BK];
    __shared__ __align__(16) ushort Bs[BN * BK];

    const int tid = threadIdx.x;
    const int lane = tid & 63, wid = tid >> 6;
    const int wm = wid >> 1, wn = wid & 1;

    // rows this thread stages (4 issues x 32 rows)
    int tokrow[4];
    #pragma unroll
    for (int it = 0; it < 4; ++it) {
        int pos = rt * BM + it * 32 + (tid >> 3);
        int cpos = min(pos, cnt - 1);
        tokrow[it] = bucket[e * n_tok + cpos] >> 1;   // token index
    }
    const ushort* wB = w1bf + (size_t)e * TWO_I * HDIM;

    f32x4 acc[4][4];
    #pragma unroll
    for (int mi = 0; mi < 4; ++mi)
        #pragma unroll
        for (int ni = 0; ni < 4; ++ni) acc[mi][ni] = (f32x4)0.f;

    for (int kt = 0; kt < HDIM / BK; ++kt) {
        const int k0 = kt * BK;
        #pragma unroll
        for (int it = 0; it < 4; ++it) {
            const ushort* sa = tA + (size_t)tokrow[it] * HDIM + k0 + (tid & 7) * 8;
            load_lds16(sa, &As[(it * 32 + wid * 8) * BK]);
            const ushort* sb = wB + (size_t)(j0 + it * 32 + (tid >> 3)) * HDIM + k0 + (tid & 7) * 8;
            load_lds16(sb, &Bs[(it * 32 + wid * 8) * BK]);
        }
        __syncthreads();
        #pragma unroll
        for (int kk = 0; kk < 2; ++kk) {
            bf16x8 a[4], b[4];
            #pragma unroll
            for (int mi = 0; mi < 4; ++mi) {
                int row = wm * 64 + mi * 16 + (lane & 15);
                a[mi] = *reinterpret_cast<const bf16x8*>(&As[row * BK + kk * 32 + (lane >> 4) * 8]);
            }
            #pragma unroll
            for (int ni = 0; ni < 4; ++ni) {
                int row = wn * 64 + ni * 16 + (lane & 15);
                b[ni] = *reinterpret_cast<const bf16x8*>(&Bs[row * BK + kk * 32 + (lane >> 4) * 8]);
            }
            #pragma unroll
            for (int mi = 0; mi < 4; ++mi)
                #pragma unroll
                for (int ni = 0; ni < 4; ++ni)
                    acc[mi][ni] = __builtin_amdgcn_mfma_f32_16x16x32_bf16(a[mi], b[ni], acc[mi][ni], 0, 0, 0);
        }
        __syncthreads();
    }

    // Epilogue: bias, pair even(gate)/odd(linear) columns via shfl_xor(1), SwiGLU
    const float* bias = b1 + e * TWO_I;
    #pragma unroll
    for (int mi = 0; mi < 4; ++mi) {
        #pragma unroll
        for (int ni = 0; ni < 4; ++ni) {
            const int ncol = wn * 64 + ni * 16 + (lane & 15);
            const int j = j0 + ncol;
            f32x4 v = acc[mi][ni];
            const float bj = bias[j];
            v.x += bj; v.y += bj; v.z += bj; v.w += bj;
            f32x4 o;
            o.x = __shfl_xor(v.x, 1, 64);
            o.y = __shfl_xor(v.y, 1, 64);
            o.z = __shfl_xor(v.z, 1, 64);
            o.w = __shfl_xor(v.w, 1, 64);
            if ((lane & 1) == 0) {
                const int icol = j >> 1;
                #pragma unroll
                for (int r = 0; r < 4; ++r) {
                    const int m = wm * 64 + mi * 16 + (lane >> 4) * 4 + r;
                    const int pos = rt * BM + m;
                    if (pos < cnt) {
                        const float xg = fminf(v[r], LIMIT);
                        const float xl = fminf(fmaxf(o[r], -LIMIT), LIMIT);
                        const float s = 1.f / (1.f + __expf(-ALPHA * xg));
                        const float hv = xg * s * (xl + 1.f);
                        const int entry = bucket[e * n_tok + pos];
                        h1[(size_t)entry * IDIM + icol] = f2bf(hv);
                    }
                }
            }
        }
    }
}

// ---------------------------------------------------------------------------
// Kernel 4: GEMM2 (gathered rows of h1) x W2[e]^T + bias, scaled by routing w,
// written to contrib[slot][tok][c].
// ---------------------------------------------------------------------------
__global__ __launch_bounds__(256) void k_gemm2(
    const ushort* __restrict__ h1, const ushort* __restrict__ w2bf,
    const float* __restrict__ b2, const float* __restrict__ route_w,
    const int* __restrict__ counts, const int* __restrict__ bucket,
    float* __restrict__ contrib, int n_tok, int rt_max)
{
    const int e  = blockIdx.x / rt_max;
    const int rt = blockIdx.x % rt_max;
    const int cnt = counts[e];
    if (rt * BM >= cnt) return;
    const int c0 = blockIdx.y * BN;

    __shared__ __align__(16) ushort As[BM * BK];
    __shared__ __align__(16) ushort Bs[BN * BK];

    const int tid = threadIdx.x;
    const int lane = tid & 63, wid = tid >> 6;
    const int wm = wid >> 1, wn = wid & 1;

    int rowent[4];
    #pragma unroll
    for (int it = 0; it < 4; ++it) {
        int pos = rt * BM + it * 32 + (tid >> 3);
        int cpos = min(pos, cnt - 1);
        rowent[it] = bucket[e * n_tok + cpos];        // tok*2+slot
    }
    const ushort* wB = w2bf + (size_t)e * HDIM * IDIM;

    f32x4 acc[4][4];
    #pragma unroll
    for (int mi = 0; mi < 4; ++mi)
        #pragma unroll
        for (int ni = 0; ni < 4; ++ni) acc[mi][ni] = (f32x4)0.f;

    for (int kt = 0; kt < IDIM / BK; ++kt) {
        const int k0 = kt * BK;
        #pragma unroll
        for (int it = 0; it < 4; ++it) {
            const ushort* sa = h1 + (size_t)rowent[it] * IDIM + k0 + (tid & 7) * 8;
            load_lds16(sa, &As[(it * 32 + wid * 8) * BK]);
            const ushort* sb = wB + (size_t)(c0 + it * 32 + (tid >> 3)) * IDIM + k0 + (tid & 7) * 8;
            load_lds16(sb, &Bs[(it * 32 + wid * 8) * BK]);
        }
        __syncthreads();
        #pragma unroll
        for (int kk = 0; kk < 2; ++kk) {
            bf16x8 a[4], b[4];
            #pragma unroll
            for (int mi = 0; mi < 4; ++mi) {
                int row = wm * 64 + mi * 16 + (lane & 15);
                a[mi] = *reinterpret_cast<const bf16x8*>(&As[row * BK + kk * 32 + (lane >> 4) * 8]);
            }
            #pragma unroll
            for (int ni = 0; ni < 4; ++ni) {
                int row = wn * 64 + ni * 16 + (lane & 15);
                b[ni] = *reinterpret_cast<const bf16x8*>(&Bs[row * BK + kk * 32 + (lane >> 4) * 8]);
            }
            #pragma unroll
            for (int mi = 0; mi < 4; ++mi)
                #pragma unroll
                for (int ni = 0; ni < 4; ++ni)
                    acc[mi][ni] = __builtin_amdgcn_mfma_f32_16x16x32_bf16(a[mi], b[ni], acc[mi][ni], 0, 0, 0);
        }
        __syncthreads();
    }

    const float* bias = b2 + e * HDIM;
    #pragma unroll
    for (int mi = 0; mi < 4; ++mi) {
        #pragma unroll
        for (int ni = 0; ni < 4; ++ni) {
            const int c = c0 + wn * 64 + ni * 16 + (lane & 15);
            f32x4 v = acc[mi][ni];
            const float bc = bias[c];
            #pragma unroll
            for (int r = 0; r < 4; ++r) {
                const int m = wm * 64 + mi * 16 + (lane >> 4) * 4 + r;
                const int pos = rt * BM + m;
                if (pos < cnt) {
                    const int entry = bucket[e * n_tok + pos];
                    const float wgt = route_w[entry];
                    const int tok = entry >> 1, slot = entry & 1;
                    contrib[((size_t)slot * n_tok + tok) * HDIM + c] = wgt * (v[r] + bc);
                }
            }
        }
    }
}

// ---------------------------------------------------------------------------
// Kernel 5: out = x + contrib[0] + contrib[1]
// ---------------------------------------------------------------------------
__global__ __launch_bounds__(256) void k_combine(
    const float* __restrict__ x, const float* __restrict__ contrib,
    float* __restrict__ out, int n4, int slot_stride4)
{
    int i = blockIdx.x * blockDim.x + threadIdx.x;
    if (i >= n4) return;
    float4 xv = reinterpret_cast<const float4*>(x)[i];
    float4 c0 = reinterpret_cast<const float4*>(contrib)[i];
    float4 c1 = reinterpret_cast<const float4*>(contrib)[i + slot_stride4];
    float4 o;
    o.x = xv.x + c0.x + c1.x;
    o.y = xv.y + c0.y + c1.y;
    o.z = xv.z + c0.z + c1.z;
    o.w = xv.w + c0.w + c1.w;
    reinterpret_cast<float4*>(out)[i] = o;
}

// ---------------------------------------------------------------------------
extern "C" void kernel_launch(void* const* d_in, const int* in_sizes, int n_in,
                              void* d_out, int out_size, void* d_ws, size_t ws_size,
                              hipStream_t stream) {
    const float* x    = (const float*)d_in[0];
    const float* nsc  = (const float*)d_in[1];
    const float* gw   = (const float*)d_in[2];
    const float* gb   = (const float*)d_in[3];
    const float* w1   = (const float*)d_in[4];
    const float* b1   = (const float*)d_in[5];
    const float* w2   = (const float*)d_in[6];
    const float* b2   = (const float*)d_in[7];
    float* out = (float*)d_out;

    const int N = in_sizes[0] / HDIM;
    const int rt_max = (N + BM - 1) / BM;

    // workspace carve-up (256B aligned)
    uintptr_t p = (uintptr_t)d_ws;
    auto carve = [&p](size_t bytes) { uintptr_t q = p; p += (bytes + 255) & ~(size_t)255; return q; };
    ushort* t_bf    = (ushort*)carve((size_t)N * HDIM * 2);
    ushort* w1bf    = (ushort*)carve((size_t)NEXP * TWO_I * HDIM * 2);
    ushort* w2bf    = (ushort*)carve((size_t)NEXP * HDIM * IDIM * 2);
    ushort* h1      = (ushort*)carve((size_t)N * TOPK * IDIM * 2);
    float*  contrib = (float*)carve((size_t)TOPK * N * HDIM * 4);
    float*  route_w = (float*)carve((size_t)N * TOPK * 4);
    int*    bucket  = (int*)carve((size_t)NEXP * N * 4);
    int*    counts  = (int*)carve(256);

    hipMemsetAsync(counts, 0, NEXP * sizeof(int), stream);

    // weight conversion fp32 -> bf16
    const int n4w1 = NEXP * TWO_I * HDIM / 4;
    const int n4w2 = NEXP * HDIM * IDIM / 4;
    k_f32_to_bf16<<<2048, 256, 0, stream>>>(w1, w1bf, n4w1);
    k_f32_to_bf16<<<2048, 256, 0, stream>>>(w2, w2bf, n4w2);

    // rmsnorm + router + scatter
    k_norm_router<<<N, 256, 0, stream>>>(x, nsc, gw, gb, t_bf, route_w, counts, bucket, N);

    // expert GEMMs
    dim3 g1(NEXP * rt_max, TWO_I / BN);
    k_gemm1<<<g1, 256, 0, stream>>>(t_bf, w1bf, b1, counts, bucket, h1, N, rt_max);
    dim3 g2(NEXP * rt_max, HDIM / BN);
    k_gemm2<<<g2, 256, 0, stream>>>(h1, w2bf, b2, route_w, counts, bucket, contrib, N, rt_max);

    // combine + residual
    const int n4 = N * HDIM / 4;
    k_combine<<<(n4 + 255) / 256, 256, 0, stream>>>(x, contrib, out, n4, n4);
}

// Round 2
// 407.716 us; speedup vs baseline: 1.6983x; 1.6983x over previous
//
#include <hip/hip_runtime.h>
#include <hip/hip_bf16.h>
#include <stdint.h>

#define HDIM 1024
#define NEXP 8
#define TOPK 2
#define IDIM 1024
#define TWO_I 2048
#define ALPHA 1.702f
#define LIMIT 7.0f
#define EPS 1e-5f

#define BM 128
#define BN 128
#define BK 64   // 64 bf16 = 128B rows, 8 chunks of 16B

typedef __attribute__((ext_vector_type(8))) short bf16x8;
typedef __attribute__((ext_vector_type(4))) float f32x4;

typedef __attribute__((address_space(1))) const uint32_t g_u32;
typedef __attribute__((address_space(3))) uint32_t l_u32;

__device__ __forceinline__ void load_lds16(const void* g, void* l) {
    // 16B/lane; LDS dest = wave-uniform base + lane*16 (linear)
    __builtin_amdgcn_global_load_lds((g_u32*)g, (l_u32*)l, 16, 0, 0);
}

__device__ __forceinline__ ushort f2bf(float f) {
    union { float f; uint32_t u; } v{f};
    uint32_t u = v.u;
    return (ushort)((u + 0x7fffu + ((u >> 16) & 1u)) >> 16);  // RNE
}

// ---------------------------------------------------------------------------
// fp32 -> bf16 convert (plain, for W2)
// ---------------------------------------------------------------------------
__global__ __launch_bounds__(256) void k_f32_to_bf16(const float* __restrict__ src,
                                                     ushort* __restrict__ dst, int n4) {
    int i = blockIdx.x * blockDim.x + threadIdx.x;
    int stride = gridDim.x * blockDim.x;
    for (; i < n4; i += stride) {
        float4 v = reinterpret_cast<const float4*>(src)[i];
        ushort4 o;
        o.x = f2bf(v.x); o.y = f2bf(v.y); o.z = f2bf(v.z); o.w = f2bf(v.w);
        reinterpret_cast<ushort4*>(dst)[i] = o;
    }
}

// ---------------------------------------------------------------------------
// fp32 -> bf16 convert + de-interleave for W1: src row j (of 2I, interleaved
// gate/linear) -> dst row (j&1)*I + (j>>1).  One block per row (1024 floats).
// ---------------------------------------------------------------------------
__global__ __launch_bounds__(256) void k_conv_w1(const float* __restrict__ src,
                                                 ushort* __restrict__ dst) {
    const int b = blockIdx.x;          // e*2I + j
    const int e = b >> 11;             // /2048
    const int j = b & 2047;
    const int dj = ((j & 1) << 10) | (j >> 1);   // (j&1)*IDIM + j/2
    const float4* s = reinterpret_cast<const float4*>(src + (size_t)b * HDIM);
    ushort4* d = reinterpret_cast<ushort4*>(dst + ((size_t)e * TWO_I + dj) * HDIM);
    float4 v = s[threadIdx.x];
    ushort4 o;
    o.x = f2bf(v.x); o.y = f2bf(v.y); o.z = f2bf(v.z); o.w = f2bf(v.w);
    d[threadIdx.x] = o;
}

// ---------------------------------------------------------------------------
// RMSNorm + router (top-2 softmax) + bucket scatter. One block per token.
// ---------------------------------------------------------------------------
__global__ __launch_bounds__(256) void k_norm_router(
    const float* __restrict__ x, const float* __restrict__ scale,
    const float* __restrict__ gw, const float* __restrict__ gb,
    ushort* __restrict__ t_bf, float* __restrict__ route_w,
    int* __restrict__ counts, int* __restrict__ bucket, int n_tok)
{
    const int n = blockIdx.x;
    const int tid = threadIdx.x;
    const int lane = tid & 63, wid = tid >> 6;

    __shared__ float red[4];
    __shared__ float gred[4][NEXP];

    const float4 xv = reinterpret_cast<const float4*>(x + (size_t)n * HDIM)[tid];
    float ss = xv.x * xv.x + xv.y * xv.y + xv.z * xv.z + xv.w * xv.w;
    #pragma unroll
    for (int off = 32; off; off >>= 1) ss += __shfl_down(ss, off, 64);
    if (lane == 0) red[wid] = ss;
    __syncthreads();
    const float tot = red[0] + red[1] + red[2] + red[3];
    const float rms = rsqrtf(tot / (float)HDIM + EPS);

    const float4 sv = reinterpret_cast<const float4*>(scale)[tid];
    float t0 = xv.x * rms * sv.x;
    float t1 = xv.y * rms * sv.y;
    float t2 = xv.z * rms * sv.z;
    float t3 = xv.w * rms * sv.w;

    ushort4 tb;
    tb.x = f2bf(t0); tb.y = f2bf(t1); tb.z = f2bf(t2); tb.w = f2bf(t3);
    reinterpret_cast<ushort4*>(t_bf + (size_t)n * HDIM)[tid] = tb;

    float g[NEXP];
    #pragma unroll
    for (int e = 0; e < NEXP; ++e) g[e] = 0.f;
    const float tv[4] = {t0, t1, t2, t3};
    const float4* gwv = reinterpret_cast<const float4*>(gw);
    #pragma unroll
    for (int j = 0; j < 4; ++j) {
        const int h = tid * 4 + j;
        const float4 a = gwv[h * 2 + 0];
        const float4 b = gwv[h * 2 + 1];
        g[0] += tv[j] * a.x; g[1] += tv[j] * a.y; g[2] += tv[j] * a.z; g[3] += tv[j] * a.w;
        g[4] += tv[j] * b.x; g[5] += tv[j] * b.y; g[6] += tv[j] * b.z; g[7] += tv[j] * b.w;
    }
    #pragma unroll
    for (int e = 0; e < NEXP; ++e) {
        #pragma unroll
        for (int off = 32; off; off >>= 1) g[e] += __shfl_down(g[e], off, 64);
    }
    if (lane == 0) {
        #pragma unroll
        for (int e = 0; e < NEXP; ++e) gred[wid][e] = g[e];
    }
    __syncthreads();

    if (tid == 0) {
        float gg[NEXP];
        #pragma unroll
        for (int e = 0; e < NEXP; ++e)
            gg[e] = gred[0][e] + gred[1][e] + gred[2][e] + gred[3][e] + gb[e];
        int i0 = 0; float l0 = gg[0];
        #pragma unroll
        for (int e = 1; e < NEXP; ++e) if (gg[e] > l0) { l0 = gg[e]; i0 = e; }
        int i1 = -1; float l1 = -3.4e38f;
        #pragma unroll
        for (int e = 0; e < NEXP; ++e) if (e != i0 && gg[e] > l1) { l1 = gg[e]; i1 = e; }
        const float w0 = 1.f / (1.f + __expf(l1 - l0));
        const float w1 = 1.f - w0;
        route_w[n * 2 + 0] = w0;
        route_w[n * 2 + 1] = w1;
        int p0 = atomicAdd(&counts[i0], 1);
        bucket[i0 * n_tok + p0] = n * 2 + 0;
        int p1 = atomicAdd(&counts[i1], 1);
        bucket[i1 * n_tok + p1] = n * 2 + 1;
    }
}

// ---------------------------------------------------------------------------
// GEMM1: gathered t rows x W1'(deinterleaved)^T + bias -> SwiGLU -> h1 (bf16)
// 128x128x64 tile, 4 waves, double-buffered LDS (2-phase), XOR-swizzled.
// Grid: 1D, id = rt*(E*16) + e*16 + jt  (rt slowest -> active blocks dense).
// Tile col group G=tc>>4: {0,1}=gate sub0,1; {2,3}=lin sub0,1; {4,5}=gate
// sub2,3; {6,7}=lin sub2,3 -> each thread holds gate col (ni) and its linear
// partner (ni+2) in the same registers.
// ---------------------------------------------------------------------------
__global__ __launch_bounds__(256) void k_gemm1(
    const ushort* __restrict__ tA, const ushort* __restrict__ w1bf,
    const float* __restrict__ b1,
    const int* __restrict__ counts, const int* __restrict__ bucket,
    ushort* __restrict__ h1, int n_tok, int rt_max)
{
    const int bx = blockIdx.x;
    const int rt = bx >> 7;            // /(NEXP*16)
    const int e  = (bx >> 4) & 7;
    const int jt = bx & 15;
    const int cnt = counts[e];
    if (rt * BM >= cnt) return;

    __shared__ __align__(16) ushort As[2][BM * BK];
    __shared__ __align__(16) ushort Bs[2][BN * BK];

    const int tid = threadIdx.x;
    const int lane = tid & 63, wid = tid >> 6;
    const int wm = wid >> 1, wn = wid & 1;

    // gathered A rows (token indices)
    int tokrow[4];
    #pragma unroll
    for (int it = 0; it < 4; ++it) {
        int pos = rt * BM + it * 32 + (tid >> 3);
        tokrow[it] = bucket[e * n_tok + min(pos, cnt - 1)] >> 1;
    }
    // B source rows from deinterleaved W1'
    const ushort* wbase = w1bf + (size_t)e * TWO_I * HDIM;
    const ushort* bsrc[4];
    #pragma unroll
    for (int it = 0; it < 4; ++it) {
        int br = it * 32 + (tid >> 3);
        int G = br >> 4, r16 = br & 15;
        int half = (G >> 1) & 1;
        int sub = ((G >> 2) << 1) | (G & 1);
        int srcrow = half * IDIM + jt * 64 + sub * 16 + r16;
        bsrc[it] = wbase + (size_t)srcrow * HDIM;
    }
    const int swz = (((tid & 7) ^ ((tid >> 3) & 7)) * 8);  // element offset in row

    f32x4 acc[4][4];
    #pragma unroll
    for (int mi = 0; mi < 4; ++mi)
        #pragma unroll
        for (int ni = 0; ni < 4; ++ni) acc[mi][ni] = (f32x4)0.f;

    auto stage = [&](int buf, int kt) {
        const int k0 = kt * BK + swz;
        #pragma unroll
        for (int it = 0; it < 4; ++it)
            load_lds16(tA + (size_t)tokrow[it] * HDIM + k0, &As[buf][(it * 32 + wid * 8) * BK]);
        #pragma unroll
        for (int it = 0; it < 4; ++it)
            load_lds16(bsrc[it] + k0, &Bs[buf][(it * 32 + wid * 8) * BK]);
    };
    auto compute = [&](int buf) {
        #pragma unroll
        for (int kk = 0; kk < 2; ++kk) {
            bf16x8 a[4], b[4];
            #pragma unroll
            for (int mi = 0; mi < 4; ++mi) {
                int r = wm * 64 + mi * 16 + (lane & 15);
                int off = r * BK + (((kk * 4 + (lane >> 4)) ^ (lane & 7)) * 8);
                a[mi] = *reinterpret_cast<const bf16x8*>(&As[buf][off]);
            }
            #pragma unroll
            for (int ni = 0; ni < 4; ++ni) {
                int r = wn * 64 + ni * 16 + (lane & 15);
                int off = r * BK + (((kk * 4 + (lane >> 4)) ^ (lane & 7)) * 8);
                b[ni] = *reinterpret_cast<const bf16x8*>(&Bs[buf][off]);
            }
            #pragma unroll
            for (int mi = 0; mi < 4; ++mi)
                #pragma unroll
                for (int ni = 0; ni < 4; ++ni)
                    acc[mi][ni] = __builtin_amdgcn_mfma_f32_16x16x32_bf16(a[mi], b[ni], acc[mi][ni], 0, 0, 0);
        }
    };

    stage(0, 0);
    __syncthreads();
    int cur = 0;
    for (int kt = 0; kt < HDIM / BK; ++kt) {
        if (kt + 1 < HDIM / BK) stage(cur ^ 1, kt + 1);
        compute(cur);
        __syncthreads();
        cur ^= 1;
    }

    // epilogue: bucket entries hoisted, SwiGLU in-thread (gate=ni, lin=ni+2)
    int ent[4][4];
    #pragma unroll
    for (int mi = 0; mi < 4; ++mi)
        #pragma unroll
        for (int r = 0; r < 4; ++r) {
            int pos = rt * BM + wm * 64 + mi * 16 + (lane >> 4) * 4 + r;
            ent[mi][r] = (pos < cnt) ? bucket[e * n_tok + pos] : -1;
        }
    #pragma unroll
    for (int ni = 0; ni < 2; ++ni) {
        const int col = jt * 64 + (wn * 2 + ni) * 16 + (lane & 15);
        const float bg = b1[e * TWO_I + 2 * col];
        const float bl = b1[e * TWO_I + 2 * col + 1];
        #pragma unroll
        for (int mi = 0; mi < 4; ++mi) {
            const f32x4 vg = acc[mi][ni];
            const f32x4 vl = acc[mi][ni + 2];
            #pragma unroll
            for (int r = 0; r < 4; ++r) {
                if (ent[mi][r] >= 0) {
                    const float xg = fminf(vg[r] + bg, LIMIT);
                    const float xl = fminf(fmaxf(vl[r] + bl, -LIMIT), LIMIT);
                    const float s = 1.f / (1.f + __expf(-ALPHA * xg));
                    h1[(size_t)ent[mi][r] * IDIM + col] = f2bf(xg * s * (xl + 1.f));
                }
            }
        }
    }
}

// ---------------------------------------------------------------------------
// GEMM2: gathered h1 rows x W2[e]^T + bias, scaled by route weight ->
// contrib[slot][tok][c].  Same 2-phase/swizzle structure.
// Grid: 1D, id = rt*(E*8) + e*8 + ct.
// ---------------------------------------------------------------------------
__global__ __launch_bounds__(256) void k_gemm2(
    const ushort* __restrict__ h1, const ushort* __restrict__ w2bf,
    const float* __restrict__ b2, const float* __restrict__ route_w,
    const int* __restrict__ counts, const int* __restrict__ bucket,
    float* __restrict__ contrib, int n_tok, int rt_max)
{
    const int bx = blockIdx.x;
    const int rt = bx >> 6;            // /(NEXP*8)
    const int e  = (bx >> 3) & 7;
    const int ct = bx & 7;
    const int cnt = counts[e];
    if (rt * BM >= cnt) return;
    const int c0 = ct * BN;

    __shared__ __align__(16) ushort As[2][BM * BK];
    __shared__ __align__(16) ushort Bs[2][BN * BK];

    const int tid = threadIdx.x;
    const int lane = tid & 63, wid = tid >> 6;
    const int wm = wid >> 1, wn = wid & 1;

    int rowent[4];
    #pragma unroll
    for (int it = 0; it < 4; ++it) {
        int pos = rt * BM + it * 32 + (tid >> 3);
        rowent[it] = bucket[e * n_tok + min(pos, cnt - 1)];
    }
    const ushort* wB = w2bf + (size_t)e * HDIM * IDIM;
    const int swz = (((tid & 7) ^ ((tid >> 3) & 7)) * 8);

    f32x4 acc[4][4];
    #pragma unroll
    for (int mi = 0; mi < 4; ++mi)
        #pragma unroll
        for (int ni = 0; ni < 4; ++ni) acc[mi][ni] = (f32x4)0.f;

    auto stage = [&](int buf, int kt) {
        const int k0 = kt * BK + swz;
        #pragma unroll
        for (int it = 0; it < 4; ++it)
            load_lds16(h1 + (size_t)rowent[it] * IDIM + k0, &As[buf][(it * 32 + wid * 8) * BK]);
        #pragma unroll
        for (int it = 0; it < 4; ++it)
            load_lds16(wB + (size_t)(c0 + it * 32 + (tid >> 3)) * IDIM + k0, &Bs[buf][(it * 32 + wid * 8) * BK]);
    };
    auto compute = [&](int buf) {
        #pragma unroll
        for (int kk = 0; kk < 2; ++kk) {
            bf16x8 a[4], b[4];
            #pragma unroll
            for (int mi = 0; mi < 4; ++mi) {
                int r = wm * 64 + mi * 16 + (lane & 15);
                int off = r * BK + (((kk * 4 + (lane >> 4)) ^ (lane & 7)) * 8);
                a[mi] = *reinterpret_cast<const bf16x8*>(&As[buf][off]);
            }
            #pragma unroll
            for (int ni = 0; ni < 4; ++ni) {
                int r = wn * 64 + ni * 16 + (lane & 15);
                int off = r * BK + (((kk * 4 + (lane >> 4)) ^ (lane & 7)) * 8);
                b[ni] = *reinterpret_cast<const bf16x8*>(&Bs[buf][off]);
            }
            #pragma unroll
            for (int mi = 0; mi < 4; ++mi)
                #pragma unroll
                for (int ni = 0; ni < 4; ++ni)
                    acc[mi][ni] = __builtin_amdgcn_mfma_f32_16x16x32_bf16(a[mi], b[ni], acc[mi][ni], 0, 0, 0);
        }
    };

    stage(0, 0);
    __syncthreads();
    int cur = 0;
    for (int kt = 0; kt < IDIM / BK; ++kt) {
        if (kt + 1 < IDIM / BK) stage(cur ^ 1, kt + 1);
        compute(cur);
        __syncthreads();
        cur ^= 1;
    }

    int ent[4][4];
    float wgt[4][4];
    #pragma unroll
    for (int mi = 0; mi < 4; ++mi)
        #pragma unroll
        for (int r = 0; r < 4; ++r) {
            int pos = rt * BM + wm * 64 + mi * 16 + (lane >> 4) * 4 + r;
            if (pos < cnt) {
                ent[mi][r] = bucket[e * n_tok + pos];
                wgt[mi][r] = route_w[ent[mi][r]];
            } else ent[mi][r] = -1;
        }
    #pragma unroll
    for (int ni = 0; ni < 4; ++ni) {
        const int c = c0 + wn * 64 + ni * 16 + (lane & 15);
        const float bc = b2[e * HDIM + c];
        #pragma unroll
        for (int mi = 0; mi < 4; ++mi) {
            const f32x4 v = acc[mi][ni];
            #pragma unroll
            for (int r = 0; r < 4; ++r) {
                if (ent[mi][r] >= 0) {
                    const int tok = ent[mi][r] >> 1, slot = ent[mi][r] & 1;
                    contrib[((size_t)slot * n_tok + tok) * HDIM + c] = wgt[mi][r] * (v[r] + bc);
                }
            }
        }
    }
}

// ---------------------------------------------------------------------------
// out = x + contrib[0] + contrib[1]
// ---------------------------------------------------------------------------
__global__ __launch_bounds__(256) void k_combine(
    const float* __restrict__ x, const float* __restrict__ contrib,
    float* __restrict__ out, int n4, int slot_stride4)
{
    int i = blockIdx.x * blockDim.x + threadIdx.x;
    if (i >= n4) return;
    float4 xv = reinterpret_cast<const float4*>(x)[i];
    float4 c0 = reinterpret_cast<const float4*>(contrib)[i];
    float4 c1 = reinterpret_cast<const float4*>(contrib)[i + slot_stride4];
    float4 o;
    o.x = xv.x + c0.x + c1.x;
    o.y = xv.y + c0.y + c1.y;
    o.z = xv.z + c0.z + c1.z;
    o.w = xv.w + c0.w + c1.w;
    reinterpret_cast<float4*>(out)[i] = o;
}

// ---------------------------------------------------------------------------
extern "C" void kernel_launch(void* const* d_in, const int* in_sizes, int n_in,
                              void* d_out, int out_size, void* d_ws, size_t ws_size,
                              hipStream_t stream) {
    const float* x    = (const float*)d_in[0];
    const float* nsc  = (const float*)d_in[1];
    const float* gw   = (const float*)d_in[2];
    const float* gb   = (const float*)d_in[3];
    const float* w1   = (const float*)d_in[4];
    const float* b1   = (const float*)d_in[5];
    const float* w2   = (const float*)d_in[6];
    const float* b2   = (const float*)d_in[7];
    float* out = (float*)d_out;

    const int N = in_sizes[0] / HDIM;
    const int rt_max = (N + BM - 1) / BM;

    uintptr_t p = (uintptr_t)d_ws;
    auto carve = [&p](size_t bytes) { uintptr_t q = p; p += (bytes + 255) & ~(size_t)255; return q; };
    ushort* t_bf    = (ushort*)carve((size_t)N * HDIM * 2);
    ushort* w1bf    = (ushort*)carve((size_t)NEXP * TWO_I * HDIM * 2);
    ushort* w2bf    = (ushort*)carve((size_t)NEXP * HDIM * IDIM * 2);
    ushort* h1      = (ushort*)carve((size_t)N * TOPK * IDIM * 2);
    float*  contrib = (float*)carve((size_t)TOPK * N * HDIM * 4);
    float*  route_w = (float*)carve((size_t)N * TOPK * 4);
    int*    bucket  = (int*)carve((size_t)NEXP * N * 4);
    int*    counts  = (int*)carve(256);

    hipMemsetAsync(counts, 0, NEXP * sizeof(int), stream);

    // weight conversion
    k_conv_w1<<<NEXP * TWO_I, 256, 0, stream>>>(w1, w1bf);
    const int n4w2 = NEXP * HDIM * IDIM / 4;
    k_f32_to_bf16<<<2048, 256, 0, stream>>>(w2, w2bf, n4w2);

    // rmsnorm + router + scatter
    k_norm_router<<<N, 256, 0, stream>>>(x, nsc, gw, gb, t_bf, route_w, counts, bucket, N);

    // expert GEMMs (rt slowest -> active blocks contiguous)
    k_gemm1<<<rt_max * NEXP * (TWO_I / BN), 256, 0, stream>>>(t_bf, w1bf, b1, counts, bucket, h1, N, rt_max);
    k_gemm2<<<rt_max * NEXP * (HDIM / BN), 256, 0, stream>>>(h1, w2bf, b2, route_w, counts, bucket, contrib, N, rt_max);

    // combine + residual
    const int n4 = N * HDIM / 4;
    k_combine<<<(n4 + 255) / 256, 256, 0, stream>>>(x, contrib, out, n4, n4);
}

// Round 4
// 337.665 us; speedup vs baseline: 2.0506x; 1.2075x over previous
//
#include <hip/hip_runtime.h>
#include <hip/hip_bf16.h>
#include <stdint.h>

#define HDIM 1024
#define NEXP 8
#define TOPK 2
#define IDIM 1024
#define TWO_I 2048
#define ALPHA 1.702f
#define LIMIT 7.0f
#define EPS 1e-5f

#define BM 128
#define BN 128
#define BK 64   // 64 bf16 = 128B rows, 8 chunks of 16B

typedef __attribute__((ext_vector_type(8))) short bf16x8;
typedef __attribute__((ext_vector_type(4))) float f32x4;

typedef __attribute__((address_space(1))) const uint32_t g_u32;
typedef __attribute__((address_space(3))) uint32_t l_u32;

__device__ __forceinline__ void load_lds16(const void* g, void* l) {
    __builtin_amdgcn_global_load_lds((g_u32*)g, (l_u32*)l, 16, 0, 0);
}

__device__ __forceinline__ ushort f2bf(float f) {
    union { float f; uint32_t u; } v{f};
    uint32_t u = v.u;
    return (ushort)((u + 0x7fffu + ((u >> 16) & 1u)) >> 16);  // RNE
}

// ---------------------------------------------------------------------------
// fp32 -> bf16 convert (plain, for W2)
// ---------------------------------------------------------------------------
__global__ __launch_bounds__(256) void k_f32_to_bf16(const float* __restrict__ src,
                                                     ushort* __restrict__ dst, int n4) {
    int i = blockIdx.x * blockDim.x + threadIdx.x;
    int stride = gridDim.x * blockDim.x;
    for (; i < n4; i += stride) {
        float4 v = reinterpret_cast<const float4*>(src)[i];
        ushort4 o;
        o.x = f2bf(v.x); o.y = f2bf(v.y); o.z = f2bf(v.z); o.w = f2bf(v.w);
        reinterpret_cast<ushort4*>(dst)[i] = o;
    }
}

// ---------------------------------------------------------------------------
// fp32 -> bf16 convert + de-interleave for W1: src row j (interleaved) ->
// dst row (j&1)*I + (j>>1).  One block per row.
// ---------------------------------------------------------------------------
__global__ __launch_bounds__(256) void k_conv_w1(const float* __restrict__ src,
                                                 ushort* __restrict__ dst) {
    const int b = blockIdx.x;          // e*2I + j
    const int e = b >> 11;
    const int j = b & 2047;
    const int dj = ((j & 1) << 10) | (j >> 1);
    const float4* s = reinterpret_cast<const float4*>(src + (size_t)b * HDIM);
    ushort4* d = reinterpret_cast<ushort4*>(dst + ((size_t)e * TWO_I + dj) * HDIM);
    float4 v = s[threadIdx.x];
    ushort4 o;
    o.x = f2bf(v.x); o.y = f2bf(v.y); o.z = f2bf(v.z); o.w = f2bf(v.w);
    d[threadIdx.x] = o;
}

// ---------------------------------------------------------------------------
// RMSNorm + gate top-2: ONE WAVE PER TOKEN. No LDS, no barriers, no atomics.
// Writes t_bf (bf16 normed), route_w[tok*2+{0,1}], eidx[tok*2+{0,1}].
// ---------------------------------------------------------------------------
__global__ __launch_bounds__(256) void k_norm_gate(
    const float* __restrict__ x, const float* __restrict__ scale,
    const float* __restrict__ gw, const float* __restrict__ gb,
    ushort* __restrict__ t_bf, float* __restrict__ route_w,
    int* __restrict__ eidx, int n_tok)
{
    const int tok = blockIdx.x * 4 + (threadIdx.x >> 6);
    if (tok >= n_tok) return;
    const int lane = threadIdx.x & 63;

    const float4* xr = reinterpret_cast<const float4*>(x + (size_t)tok * HDIM);
    const float4* sr = reinterpret_cast<const float4*>(scale);
    float4 xv[4], sv[4];
    #pragma unroll
    for (int j = 0; j < 4; ++j) { xv[j] = xr[lane + 64 * j]; sv[j] = sr[lane + 64 * j]; }

    float ss = 0.f;
    #pragma unroll
    for (int j = 0; j < 4; ++j)
        ss += xv[j].x * xv[j].x + xv[j].y * xv[j].y + xv[j].z * xv[j].z + xv[j].w * xv[j].w;
    #pragma unroll
    for (int off = 1; off < 64; off <<= 1) ss += __shfl_xor(ss, off, 64);
    const float rms = rsqrtf(ss / (float)HDIM + EPS);

    float t[4][4];
    ushort4* tw = reinterpret_cast<ushort4*>(t_bf + (size_t)tok * HDIM);
    #pragma unroll
    for (int j = 0; j < 4; ++j) {
        t[j][0] = xv[j].x * rms * sv[j].x;
        t[j][1] = xv[j].y * rms * sv[j].y;
        t[j][2] = xv[j].z * rms * sv[j].z;
        t[j][3] = xv[j].w * rms * sv[j].w;
        ushort4 o;
        o.x = f2bf(t[j][0]); o.y = f2bf(t[j][1]); o.z = f2bf(t[j][2]); o.w = f2bf(t[j][3]);
        tw[lane + 64 * j] = o;
    }

    // gate logits: g[e] = sum_h t[h]*gw[h][e]
    float g[NEXP];
    #pragma unroll
    for (int e = 0; e < NEXP; ++e) g[e] = 0.f;
    const float4* gwv = reinterpret_cast<const float4*>(gw);
    #pragma unroll
    for (int j = 0; j < 4; ++j) {
        #pragma unroll
        for (int c = 0; c < 4; ++c) {
            const int h = (lane + 64 * j) * 4 + c;
            const float tv = t[j][c];
            const float4 a = gwv[h * 2 + 0];
            const float4 b = gwv[h * 2 + 1];
            g[0] += tv * a.x; g[1] += tv * a.y; g[2] += tv * a.z; g[3] += tv * a.w;
            g[4] += tv * b.x; g[5] += tv * b.y; g[6] += tv * b.z; g[7] += tv * b.w;
        }
    }
    #pragma unroll
    for (int e = 0; e < NEXP; ++e) {
        #pragma unroll
        for (int off = 1; off < 64; off <<= 1) g[e] += __shfl_xor(g[e], off, 64);
    }

    if (lane == 0) {
        float gg[NEXP];
        #pragma unroll
        for (int e = 0; e < NEXP; ++e) gg[e] = g[e] + gb[e];
        int i0 = 0; float l0 = gg[0];
        #pragma unroll
        for (int e = 1; e < NEXP; ++e) if (gg[e] > l0) { l0 = gg[e]; i0 = e; }
        int i1 = -1; float l1 = -3.4e38f;
        #pragma unroll
        for (int e = 0; e < NEXP; ++e) if (e != i0 && gg[e] > l1) { l1 = gg[e]; i1 = e; }
        const float w0 = 1.f / (1.f + __expf(l1 - l0));
        route_w[tok * 2 + 0] = w0;
        route_w[tok * 2 + 1] = 1.f - w0;
        eidx[tok * 2 + 0] = i0;
        eidx[tok * 2 + 1] = i1;
    }
}

// ---------------------------------------------------------------------------
// Bucket build: 8 blocks x 256 thr. Ballot-based wave ranking + LDS prefix;
// only 8 global atomicAdds per block (one per expert). Order within an
// expert's bucket is arbitrary (entries are a set).
// ---------------------------------------------------------------------------
#define BKT_BLOCKS 8
__global__ __launch_bounds__(256) void k_bucket(
    const int* __restrict__ eidx, int* __restrict__ counts,
    int* __restrict__ bucket, int n_tok)
{
    const int total = 2 * n_tok;
    const int per_block = total / BKT_BLOCKS;       // 1024
    const int rounds = per_block / 256;             // 4
    const int base_ent = blockIdx.x * per_block;
    const int tid = threadIdx.x;
    const int lane = tid & 63, wid = tid >> 6;

    __shared__ int wavecnt[4][4][NEXP];   // [round][wave][expert]
    __shared__ int cum[4][4][NEXP];
    __shared__ int gbase[NEXP];

    int me[4], rank[4];
    #pragma unroll
    for (int r = 0; r < 4; ++r) {
        const int ent = base_ent + r * 256 + tid;
        const int e = (r < rounds) ? eidx[ent] : -1;
        me[r] = e;
        #pragma unroll
        for (int ex = 0; ex < NEXP; ++ex) {
            unsigned long long m = __ballot(e == ex);
            if (e == ex) rank[r] = __popcll(m & ((1ull << lane) - 1ull));
            if (lane == 0) wavecnt[r][wid][ex] = (int)__popcll(m);
        }
    }
    __syncthreads();

    // prefix over (round, wave) in round-major order + global base per expert
    if (tid < 4 * 4 * NEXP) {
        const int e = tid & 7, w = (tid >> 3) & 3, r = tid >> 5;
        int s = 0;
        for (int rr = 0; rr < 4; ++rr)
            for (int ww = 0; ww < 4; ++ww)
                if (rr < r || (rr == r && ww < w)) s += wavecnt[rr][ww][e];
        cum[r][w][e] = s;
    }
    __syncthreads();
    if (tid < NEXP) {
        int tot = 0;
        for (int rr = 0; rr < 4; ++rr)
            for (int ww = 0; ww < 4; ++ww) tot += wavecnt[rr][ww][tid];
        gbase[tid] = atomicAdd(&counts[tid], tot);
    }
    __syncthreads();

    #pragma unroll
    for (int r = 0; r < 4; ++r) {
        const int e = me[r];
        if (e >= 0) {
            const int ent = base_ent + r * 256 + tid;
            bucket[e * n_tok + gbase[e] + cum[r][wid][e] + rank[r]] = ent;
        }
    }
}

// ---------------------------------------------------------------------------
// GEMM1: gathered t rows x W1'(deinterleaved)^T + bias -> SwiGLU -> h1 (bf16)
// 128x128x64 tile, 4 waves, double-buffered LDS (2-phase), XOR-swizzled.
// ---------------------------------------------------------------------------
__global__ __launch_bounds__(256) void k_gemm1(
    const ushort* __restrict__ tA, const ushort* __restrict__ w1bf,
    const float* __restrict__ b1,
    const int* __restrict__ counts, const int* __restrict__ bucket,
    ushort* __restrict__ h1, int n_tok, int rt_max)
{
    const int bx = blockIdx.x;
    const int rt = bx >> 7;
    const int e  = (bx >> 4) & 7;
    const int jt = bx & 15;
    const int cnt = counts[e];
    if (rt * BM >= cnt) return;

    __shared__ __align__(16) ushort As[2][BM * BK];
    __shared__ __align__(16) ushort Bs[2][BN * BK];

    const int tid = threadIdx.x;
    const int lane = tid & 63, wid = tid >> 6;
    const int wm = wid >> 1, wn = wid & 1;

    int tokrow[4];
    #pragma unroll
    for (int it = 0; it < 4; ++it) {
        int pos = rt * BM + it * 32 + (tid >> 3);
        tokrow[it] = bucket[e * n_tok + min(pos, cnt - 1)] >> 1;
    }
    const ushort* wbase = w1bf + (size_t)e * TWO_I * HDIM;
    const ushort* bsrc[4];
    #pragma unroll
    for (int it = 0; it < 4; ++it) {
        int br = it * 32 + (tid >> 3);
        int G = br >> 4, r16 = br & 15;
        int half = (G >> 1) & 1;
        int sub = ((G >> 2) << 1) | (G & 1);
        int srcrow = half * IDIM + jt * 64 + sub * 16 + r16;
        bsrc[it] = wbase + (size_t)srcrow * HDIM;
    }
    const int swz = (((tid & 7) ^ ((tid >> 3) & 7)) * 8);

    f32x4 acc[4][4];
    #pragma unroll
    for (int mi = 0; mi < 4; ++mi)
        #pragma unroll
        for (int ni = 0; ni < 4; ++ni) acc[mi][ni] = (f32x4)0.f;

    auto stage = [&](int buf, int kt) {
        const int k0 = kt * BK + swz;
        #pragma unroll
        for (int it = 0; it < 4; ++it)
            load_lds16(tA + (size_t)tokrow[it] * HDIM + k0, &As[buf][(it * 32 + wid * 8) * BK]);
        #pragma unroll
        for (int it = 0; it < 4; ++it)
            load_lds16(bsrc[it] + k0, &Bs[buf][(it * 32 + wid * 8) * BK]);
    };
    auto compute = [&](int buf) {
        #pragma unroll
        for (int kk = 0; kk < 2; ++kk) {
            bf16x8 a[4], b[4];
            #pragma unroll
            for (int mi = 0; mi < 4; ++mi) {
                int r = wm * 64 + mi * 16 + (lane & 15);
                int off = r * BK + (((kk * 4 + (lane >> 4)) ^ (lane & 7)) * 8);
                a[mi] = *reinterpret_cast<const bf16x8*>(&As[buf][off]);
            }
            #pragma unroll
            for (int ni = 0; ni < 4; ++ni) {
                int r = wn * 64 + ni * 16 + (lane & 15);
                int off = r * BK + (((kk * 4 + (lane >> 4)) ^ (lane & 7)) * 8);
                b[ni] = *reinterpret_cast<const bf16x8*>(&Bs[buf][off]);
            }
            #pragma unroll
            for (int mi = 0; mi < 4; ++mi)
                #pragma unroll
                for (int ni = 0; ni < 4; ++ni)
                    acc[mi][ni] = __builtin_amdgcn_mfma_f32_16x16x32_bf16(a[mi], b[ni], acc[mi][ni], 0, 0, 0);
        }
    };

    stage(0, 0);
    __syncthreads();
    int cur = 0;
    for (int kt = 0; kt < HDIM / BK; ++kt) {
        if (kt + 1 < HDIM / BK) stage(cur ^ 1, kt + 1);
        compute(cur);
        __syncthreads();
        cur ^= 1;
    }

    int ent[4][4];
    #pragma unroll
    for (int mi = 0; mi < 4; ++mi)
        #pragma unroll
        for (int r = 0; r < 4; ++r) {
            int pos = rt * BM + wm * 64 + mi * 16 + (lane >> 4) * 4 + r;
            ent[mi][r] = (pos < cnt) ? bucket[e * n_tok + pos] : -1;
        }
    #pragma unroll
    for (int ni = 0; ni < 2; ++ni) {
        const int col = jt * 64 + (wn * 2 + ni) * 16 + (lane & 15);
        const float bg = b1[e * TWO_I + 2 * col];
        const float bl = b1[e * TWO_I + 2 * col + 1];
        #pragma unroll
        for (int mi = 0; mi < 4; ++mi) {
            const f32x4 vg = acc[mi][ni];
            const f32x4 vl = acc[mi][ni + 2];
            #pragma unroll
            for (int r = 0; r < 4; ++r) {
                if (ent[mi][r] >= 0) {
                    const float xg = fminf(vg[r] + bg, LIMIT);
                    const float xl = fminf(fmaxf(vl[r] + bl, -LIMIT), LIMIT);
                    const float s = 1.f / (1.f + __expf(-ALPHA * xg));
                    h1[(size_t)ent[mi][r] * IDIM + col] = f2bf(xg * s * (xl + 1.f));
                }
            }
        }
    }
}

// ---------------------------------------------------------------------------
// GEMM2: gathered h1 rows x W2[e]^T + bias, * route weight -> contrib
// ---------------------------------------------------------------------------
__global__ __launch_bounds__(256) void k_gemm2(
    const ushort* __restrict__ h1, const ushort* __restrict__ w2bf,
    const float* __restrict__ b2, const float* __restrict__ route_w,
    const int* __restrict__ counts, const int* __restrict__ bucket,
    float* __restrict__ contrib, int n_tok, int rt_max)
{
    const int bx = blockIdx.x;
    const int rt = bx >> 6;
    const int e  = (bx >> 3) & 7;
    const int ct = bx & 7;
    const int cnt = counts[e];
    if (rt * BM >= cnt) return;
    const int c0 = ct * BN;

    __shared__ __align__(16) ushort As[2][BM * BK];
    __shared__ __align__(16) ushort Bs[2][BN * BK];

    const int tid = threadIdx.x;
    const int lane = tid & 63, wid = tid >> 6;
    const int wm = wid >> 1, wn = wid & 1;

    int rowent[4];
    #pragma unroll
    for (int it = 0; it < 4; ++it) {
        int pos = rt * BM + it * 32 + (tid >> 3);
        rowent[it] = bucket[e * n_tok + min(pos, cnt - 1)];
    }
    const ushort* wB = w2bf + (size_t)e * HDIM * IDIM;
    const int swz = (((tid & 7) ^ ((tid >> 3) & 7)) * 8);

    f32x4 acc[4][4];
    #pragma unroll
    for (int mi = 0; mi < 4; ++mi)
        #pragma unroll
        for (int ni = 0; ni < 4; ++ni) acc[mi][ni] = (f32x4)0.f;

    auto stage = [&](int buf, int kt) {
        const int k0 = kt * BK + swz;
        #pragma unroll
        for (int it = 0; it < 4; ++it)
            load_lds16(h1 + (size_t)rowent[it] * IDIM + k0, &As[buf][(it * 32 + wid * 8) * BK]);
        #pragma unroll
        for (int it = 0; it < 4; ++it)
            load_lds16(wB + (size_t)(c0 + it * 32 + (tid >> 3)) * IDIM + k0, &Bs[buf][(it * 32 + wid * 8) * BK]);
    };
    auto compute = [&](int buf) {
        #pragma unroll
        for (int kk = 0; kk < 2; ++kk) {
            bf16x8 a[4], b[4];
            #pragma unroll
            for (int mi = 0; mi < 4; ++mi) {
                int r = wm * 64 + mi * 16 + (lane & 15);
                int off = r * BK + (((kk * 4 + (lane >> 4)) ^ (lane & 7)) * 8);
                a[mi] = *reinterpret_cast<const bf16x8*>(&As[buf][off]);
            }
            #pragma unroll
            for (int ni = 0; ni < 4; ++ni) {
                int r = wn * 64 + ni * 16 + (lane & 15);
                int off = r * BK + (((kk * 4 + (lane >> 4)) ^ (lane & 7)) * 8);
                b[ni] = *reinterpret_cast<const bf16x8*>(&Bs[buf][off]);
            }
            #pragma unroll
            for (int mi = 0; mi < 4; ++mi)
                #pragma unroll
                for (int ni = 0; ni < 4; ++ni)
                    acc[mi][ni] = __builtin_amdgcn_mfma_f32_16x16x32_bf16(a[mi], b[ni], acc[mi][ni], 0, 0, 0);
        }
    };

    stage(0, 0);
    __syncthreads();
    int cur = 0;
    for (int kt = 0; kt < IDIM / BK; ++kt) {
        if (kt + 1 < IDIM / BK) stage(cur ^ 1, kt + 1);
        compute(cur);
        __syncthreads();
        cur ^= 1;
    }

    int ent[4][4];
    float wgt[4][4];
    #pragma unroll
    for (int mi = 0; mi < 4; ++mi)
        #pragma unroll
        for (int r = 0; r < 4; ++r) {
            int pos = rt * BM + wm * 64 + mi * 16 + (lane >> 4) * 4 + r;
            if (pos < cnt) {
                ent[mi][r] = bucket[e * n_tok + pos];
                wgt[mi][r] = route_w[ent[mi][r]];
            } else ent[mi][r] = -1;
        }
    #pragma unroll
    for (int ni = 0; ni < 4; ++ni) {
        const int c = c0 + wn * 64 + ni * 16 + (lane & 15);
        const float bc = b2[e * HDIM + c];
        #pragma unroll
        for (int mi = 0; mi < 4; ++mi) {
            const f32x4 v = acc[mi][ni];
            #pragma unroll
            for (int r = 0; r < 4; ++r) {
                if (ent[mi][r] >= 0) {
                    const int tok = ent[mi][r] >> 1, slot = ent[mi][r] & 1;
                    contrib[((size_t)slot * n_tok + tok) * HDIM + c] = wgt[mi][r] * (v[r] + bc);
                }
            }
        }
    }
}

// ---------------------------------------------------------------------------
// out = x + contrib[0] + contrib[1]
// ---------------------------------------------------------------------------
__global__ __launch_bounds__(256) void k_combine(
    const float* __restrict__ x, const float* __restrict__ contrib,
    float* __restrict__ out, int n4, int slot_stride4)
{
    int i = blockIdx.x * blockDim.x + threadIdx.x;
    if (i >= n4) return;
    float4 xv = reinterpret_cast<const float4*>(x)[i];
    float4 c0 = reinterpret_cast<const float4*>(contrib)[i];
    float4 c1 = reinterpret_cast<const float4*>(contrib)[i + slot_stride4];
    float4 o;
    o.x = xv.x + c0.x + c1.x;
    o.y = xv.y + c0.y + c1.y;
    o.z = xv.z + c0.z + c1.z;
    o.w = xv.w + c0.w + c1.w;
    reinterpret_cast<float4*>(out)[i] = o;
}

// ---------------------------------------------------------------------------
extern "C" void kernel_launch(void* const* d_in, const int* in_sizes, int n_in,
                              void* d_out, int out_size, void* d_ws, size_t ws_size,
                              hipStream_t stream) {
    const float* x    = (const float*)d_in[0];
    const float* nsc  = (const float*)d_in[1];
    const float* gw   = (const float*)d_in[2];
    const float* gb   = (const float*)d_in[3];
    const float* w1   = (const float*)d_in[4];
    const float* b1   = (const float*)d_in[5];
    const float* w2   = (const float*)d_in[6];
    const float* b2   = (const float*)d_in[7];
    float* out = (float*)d_out;

    const int N = in_sizes[0] / HDIM;
    const int rt_max = (N + BM - 1) / BM;

    uintptr_t p = (uintptr_t)d_ws;
    auto carve = [&p](size_t bytes) { uintptr_t q = p; p += (bytes + 255) & ~(size_t)255; return q; };
    ushort* t_bf    = (ushort*)carve((size_t)N * HDIM * 2);
    ushort* w1bf    = (ushort*)carve((size_t)NEXP * TWO_I * HDIM * 2);
    ushort* w2bf    = (ushort*)carve((size_t)NEXP * HDIM * IDIM * 2);
    ushort* h1      = (ushort*)carve((size_t)N * TOPK * IDIM * 2);
    float*  contrib = (float*)carve((size_t)TOPK * N * HDIM * 4);
    float*  route_w = (float*)carve((size_t)N * TOPK * 4);
    int*    bucket  = (int*)carve((size_t)NEXP * N * 4);
    int*    eidx    = (int*)carve((size_t)N * TOPK * 4);
    int*    counts  = (int*)carve(256);

    hipMemsetAsync(counts, 0, NEXP * sizeof(int), stream);

    // weight conversion
    k_conv_w1<<<NEXP * TWO_I, 256, 0, stream>>>(w1, w1bf);
    const int n4w2 = NEXP * HDIM * IDIM / 4;
    k_f32_to_bf16<<<2048, 256, 0, stream>>>(w2, w2bf, n4w2);

    // rmsnorm + gate (wave per token), then ballot-based bucket build
    k_norm_gate<<<(N + 3) / 4, 256, 0, stream>>>(x, nsc, gw, gb, t_bf, route_w, eidx, N);
    k_bucket<<<BKT_BLOCKS, 256, 0, stream>>>(eidx, counts, bucket, N);

    // expert GEMMs (rt slowest -> active blocks contiguous)
    k_gemm1<<<rt_max * NEXP * (TWO_I / BN), 256, 0, stream>>>(t_bf, w1bf, b1, counts, bucket, h1, N, rt_max);
    k_gemm2<<<rt_max * NEXP * (HDIM / BN), 256, 0, stream>>>(h1, w2bf, b2, route_w, counts, bucket, contrib, N, rt_max);

    // combine + residual
    const int n4 = N * HDIM / 4;
    k_combine<<<(n4 + 255) / 256, 256, 0, stream>>>(x, contrib, out, n4, n4);
}

// Round 5
// 327.992 us; speedup vs baseline: 2.1111x; 1.0295x over previous
//
#include <hip/hip_runtime.h>
#include <hip/hip_bf16.h>
#include <stdint.h>

#define HDIM 1024
#define NEXP 8
#define TOPK 2
#define IDIM 1024
#define TWO_I 2048
#define ALPHA 1.702f
#define LIMIT 7.0f
#define EPS 1e-5f

#define BM 128
#define BN 128
#define BK 64   // 64 bf16 = 128B rows, 8 chunks of 16B

typedef __attribute__((ext_vector_type(8))) short bf16x8;
typedef __attribute__((ext_vector_type(4))) float f32x4;

typedef __attribute__((address_space(1))) const uint32_t g_u32;
typedef __attribute__((address_space(3))) uint32_t l_u32;

__device__ __forceinline__ void load_lds16(const void* g, void* l) {
    __builtin_amdgcn_global_load_lds((g_u32*)g, (l_u32*)l, 16, 0, 0);
}

__device__ __forceinline__ ushort f2bf(float f) {
    union { float f; uint32_t u; } v{f};
    uint32_t u = v.u;
    return (ushort)((u + 0x7fffu + ((u >> 16) & 1u)) >> 16);  // RNE
}

// counted-vmcnt waits (T4): keep prefetch loads in flight across barriers.
#define WAIT_VM8()  do { asm volatile("s_waitcnt vmcnt(8)" ::: "memory"); \
                         __builtin_amdgcn_sched_barrier(0); } while (0)
#define WAIT_VM0()  do { asm volatile("s_waitcnt vmcnt(0)" ::: "memory"); \
                         __builtin_amdgcn_sched_barrier(0); } while (0)
#define BAR()       do { __builtin_amdgcn_sched_barrier(0); \
                         __builtin_amdgcn_s_barrier(); \
                         __builtin_amdgcn_sched_barrier(0); } while (0)

// ---------------------------------------------------------------------------
// fp32 -> bf16 convert (plain, for W2)
// ---------------------------------------------------------------------------
__global__ __launch_bounds__(256) void k_f32_to_bf16(const float* __restrict__ src,
                                                     ushort* __restrict__ dst, int n4) {
    int i = blockIdx.x * blockDim.x + threadIdx.x;
    int stride = gridDim.x * blockDim.x;
    for (; i < n4; i += stride) {
        float4 v = reinterpret_cast<const float4*>(src)[i];
        ushort4 o;
        o.x = f2bf(v.x); o.y = f2bf(v.y); o.z = f2bf(v.z); o.w = f2bf(v.w);
        reinterpret_cast<ushort4*>(dst)[i] = o;
    }
}

// ---------------------------------------------------------------------------
// fp32 -> bf16 convert + de-interleave for W1: src row j (interleaved) ->
// dst row (j&1)*I + (j>>1).  One block per row.
// ---------------------------------------------------------------------------
__global__ __launch_bounds__(256) void k_conv_w1(const float* __restrict__ src,
                                                 ushort* __restrict__ dst) {
    const int b = blockIdx.x;          // e*2I + j
    const int e = b >> 11;
    const int j = b & 2047;
    const int dj = ((j & 1) << 10) | (j >> 1);
    const float4* s = reinterpret_cast<const float4*>(src + (size_t)b * HDIM);
    ushort4* d = reinterpret_cast<ushort4*>(dst + ((size_t)e * TWO_I + dj) * HDIM);
    float4 v = s[threadIdx.x];
    ushort4 o;
    o.x = f2bf(v.x); o.y = f2bf(v.y); o.z = f2bf(v.z); o.w = f2bf(v.w);
    d[threadIdx.x] = o;
}

// ---------------------------------------------------------------------------
// RMSNorm + gate top-2: ONE WAVE PER TOKEN. No LDS, no barriers, no atomics.
// ---------------------------------------------------------------------------
__global__ __launch_bounds__(256) void k_norm_gate(
    const float* __restrict__ x, const float* __restrict__ scale,
    const float* __restrict__ gw, const float* __restrict__ gb,
    ushort* __restrict__ t_bf, float* __restrict__ route_w,
    int* __restrict__ eidx, int n_tok)
{
    const int tok = blockIdx.x * 4 + (threadIdx.x >> 6);
    if (tok >= n_tok) return;
    const int lane = threadIdx.x & 63;

    const float4* xr = reinterpret_cast<const float4*>(x + (size_t)tok * HDIM);
    const float4* sr = reinterpret_cast<const float4*>(scale);
    float4 xv[4], sv[4];
    #pragma unroll
    for (int j = 0; j < 4; ++j) { xv[j] = xr[lane + 64 * j]; sv[j] = sr[lane + 64 * j]; }

    float ss = 0.f;
    #pragma unroll
    for (int j = 0; j < 4; ++j)
        ss += xv[j].x * xv[j].x + xv[j].y * xv[j].y + xv[j].z * xv[j].z + xv[j].w * xv[j].w;
    #pragma unroll
    for (int off = 1; off < 64; off <<= 1) ss += __shfl_xor(ss, off, 64);
    const float rms = rsqrtf(ss / (float)HDIM + EPS);

    float t[4][4];
    ushort4* tw = reinterpret_cast<ushort4*>(t_bf + (size_t)tok * HDIM);
    #pragma unroll
    for (int j = 0; j < 4; ++j) {
        t[j][0] = xv[j].x * rms * sv[j].x;
        t[j][1] = xv[j].y * rms * sv[j].y;
        t[j][2] = xv[j].z * rms * sv[j].z;
        t[j][3] = xv[j].w * rms * sv[j].w;
        ushort4 o;
        o.x = f2bf(t[j][0]); o.y = f2bf(t[j][1]); o.z = f2bf(t[j][2]); o.w = f2bf(t[j][3]);
        tw[lane + 64 * j] = o;
    }

    float g[NEXP];
    #pragma unroll
    for (int e = 0; e < NEXP; ++e) g[e] = 0.f;
    const float4* gwv = reinterpret_cast<const float4*>(gw);
    #pragma unroll
    for (int j = 0; j < 4; ++j) {
        #pragma unroll
        for (int c = 0; c < 4; ++c) {
            const int h = (lane + 64 * j) * 4 + c;
            const float tv = t[j][c];
            const float4 a = gwv[h * 2 + 0];
            const float4 b = gwv[h * 2 + 1];
            g[0] += tv * a.x; g[1] += tv * a.y; g[2] += tv * a.z; g[3] += tv * a.w;
            g[4] += tv * b.x; g[5] += tv * b.y; g[6] += tv * b.z; g[7] += tv * b.w;
        }
    }
    #pragma unroll
    for (int e = 0; e < NEXP; ++e) {
        #pragma unroll
        for (int off = 1; off < 64; off <<= 1) g[e] += __shfl_xor(g[e], off, 64);
    }

    if (lane == 0) {
        float gg[NEXP];
        #pragma unroll
        for (int e = 0; e < NEXP; ++e) gg[e] = g[e] + gb[e];
        int i0 = 0; float l0 = gg[0];
        #pragma unroll
        for (int e = 1; e < NEXP; ++e) if (gg[e] > l0) { l0 = gg[e]; i0 = e; }
        int i1 = -1; float l1 = -3.4e38f;
        #pragma unroll
        for (int e = 0; e < NEXP; ++e) if (e != i0 && gg[e] > l1) { l1 = gg[e]; i1 = e; }
        const float w0 = 1.f / (1.f + __expf(l1 - l0));
        route_w[tok * 2 + 0] = w0;
        route_w[tok * 2 + 1] = 1.f - w0;
        eidx[tok * 2 + 0] = i0;
        eidx[tok * 2 + 1] = i1;
    }
}

// ---------------------------------------------------------------------------
// Bucket build: ballot ranking + LDS prefix; 8 atomics per block.
// ---------------------------------------------------------------------------
#define BKT_BLOCKS 8
__global__ __launch_bounds__(256) void k_bucket(
    const int* __restrict__ eidx, int* __restrict__ counts,
    int* __restrict__ bucket, int n_tok)
{
    const int total = 2 * n_tok;
    const int per_block = total / BKT_BLOCKS;
    const int rounds = per_block / 256;
    const int base_ent = blockIdx.x * per_block;
    const int tid = threadIdx.x;
    const int lane = tid & 63, wid = tid >> 6;

    __shared__ int wavecnt[4][4][NEXP];
    __shared__ int cum[4][4][NEXP];
    __shared__ int gbase[NEXP];

    int me[4], rank[4];
    #pragma unroll
    for (int r = 0; r < 4; ++r) {
        const int ent = base_ent + r * 256 + tid;
        const int e = (r < rounds) ? eidx[ent] : -1;
        me[r] = e;
        #pragma unroll
        for (int ex = 0; ex < NEXP; ++ex) {
            unsigned long long m = __ballot(e == ex);
            if (e == ex) rank[r] = __popcll(m & ((1ull << lane) - 1ull));
            if (lane == 0) wavecnt[r][wid][ex] = (int)__popcll(m);
        }
    }
    __syncthreads();

    if (tid < 4 * 4 * NEXP) {
        const int e = tid & 7, w = (tid >> 3) & 3, r = tid >> 5;
        int s = 0;
        for (int rr = 0; rr < 4; ++rr)
            for (int ww = 0; ww < 4; ++ww)
                if (rr < r || (rr == r && ww < w)) s += wavecnt[rr][ww][e];
        cum[r][w][e] = s;
    }
    __syncthreads();
    if (tid < NEXP) {
        int tot = 0;
        for (int rr = 0; rr < 4; ++rr)
            for (int ww = 0; ww < 4; ++ww) tot += wavecnt[rr][ww][tid];
        gbase[tid] = atomicAdd(&counts[tid], tot);
    }
    __syncthreads();

    #pragma unroll
    for (int r = 0; r < 4; ++r) {
        const int e = me[r];
        if (e >= 0) {
            const int ent = base_ent + r * 256 + tid;
            bucket[e * n_tok + gbase[e] + cum[r][wid][e] + rank[r]] = ent;
        }
    }
}

// ---------------------------------------------------------------------------
// GEMM1: gathered t rows x W1'^T + bias -> SwiGLU -> h1 (bf16).
// 128x128x64, 4 waves, dbuf LDS, XOR-swizzle, counted-vmcnt pipeline (T4).
// ---------------------------------------------------------------------------
__global__ __launch_bounds__(256) void k_gemm1(
    const ushort* __restrict__ tA, const ushort* __restrict__ w1bf,
    const float* __restrict__ b1,
    const int* __restrict__ counts, const int* __restrict__ bucket,
    ushort* __restrict__ h1, int n_tok, int rt_max)
{
    const int bx = blockIdx.x;
    const int rt = bx >> 7;
    const int e  = (bx >> 4) & 7;
    const int jt = bx & 15;
    const int cnt = counts[e];
    if (rt * BM >= cnt) return;

    __shared__ __align__(16) ushort As[2][BM * BK];
    __shared__ __align__(16) ushort Bs[2][BN * BK];

    const int tid = threadIdx.x;
    const int lane = tid & 63, wid = tid >> 6;
    const int wm = wid >> 1, wn = wid & 1;

    int tokrow[4];
    #pragma unroll
    for (int it = 0; it < 4; ++it) {
        int pos = rt * BM + it * 32 + (tid >> 3);
        tokrow[it] = bucket[e * n_tok + min(pos, cnt - 1)] >> 1;
    }
    const ushort* wbase = w1bf + (size_t)e * TWO_I * HDIM;
    const ushort* bsrc[4];
    #pragma unroll
    for (int it = 0; it < 4; ++it) {
        int br = it * 32 + (tid >> 3);
        int G = br >> 4, r16 = br & 15;
        int half = (G >> 1) & 1;
        int sub = ((G >> 2) << 1) | (G & 1);
        int srcrow = half * IDIM + jt * 64 + sub * 16 + r16;
        bsrc[it] = wbase + (size_t)srcrow * HDIM;
    }
    const int swz = (((tid & 7) ^ ((tid >> 3) & 7)) * 8);

    f32x4 acc[4][4];
    #pragma unroll
    for (int mi = 0; mi < 4; ++mi)
        #pragma unroll
        for (int ni = 0; ni < 4; ++ni) acc[mi][ni] = (f32x4)0.f;

    auto stage = [&](int buf, int kt) {
        const int k0 = kt * BK + swz;
        #pragma unroll
        for (int it = 0; it < 4; ++it)
            load_lds16(tA + (size_t)tokrow[it] * HDIM + k0, &As[buf][(it * 32 + wid * 8) * BK]);
        #pragma unroll
        for (int it = 0; it < 4; ++it)
            load_lds16(bsrc[it] + k0, &Bs[buf][(it * 32 + wid * 8) * BK]);
    };
    auto compute = [&](int buf) {
        #pragma unroll
        for (int kk = 0; kk < 2; ++kk) {
            bf16x8 a[4], b[4];
            #pragma unroll
            for (int mi = 0; mi < 4; ++mi) {
                int r = wm * 64 + mi * 16 + (lane & 15);
                int off = r * BK + (((kk * 4 + (lane >> 4)) ^ (lane & 7)) * 8);
                a[mi] = *reinterpret_cast<const bf16x8*>(&As[buf][off]);
            }
            #pragma unroll
            for (int ni = 0; ni < 4; ++ni) {
                int r = wn * 64 + ni * 16 + (lane & 15);
                int off = r * BK + (((kk * 4 + (lane >> 4)) ^ (lane & 7)) * 8);
                b[ni] = *reinterpret_cast<const bf16x8*>(&Bs[buf][off]);
            }
            #pragma unroll
            for (int mi = 0; mi < 4; ++mi)
                #pragma unroll
                for (int ni = 0; ni < 4; ++ni)
                    acc[mi][ni] = __builtin_amdgcn_mfma_f32_16x16x32_bf16(a[mi], b[ni], acc[mi][ni], 0, 0, 0);
        }
    };

    // T4 pipeline: next tile's 8 loads stay in flight across barriers.
    stage(0, 0);
    int cur = 0;
    for (int kt = 0; kt < HDIM / BK - 1; ++kt) {
        stage(cur ^ 1, kt + 1);   // 16 outstanding
        WAIT_VM8();               // tile kt landed (own wave)
        BAR();                    // all waves landed tile kt
        compute(cur);
        BAR();                    // all waves done reading buf before overwrite
        cur ^= 1;
    }
    WAIT_VM0();
    BAR();
    compute(cur);

    int ent[4][4];
    #pragma unroll
    for (int mi = 0; mi < 4; ++mi)
        #pragma unroll
        for (int r = 0; r < 4; ++r) {
            int pos = rt * BM + wm * 64 + mi * 16 + (lane >> 4) * 4 + r;
            ent[mi][r] = (pos < cnt) ? bucket[e * n_tok + pos] : -1;
        }
    #pragma unroll
    for (int ni = 0; ni < 2; ++ni) {
        const int col = jt * 64 + (wn * 2 + ni) * 16 + (lane & 15);
        const float bg = b1[e * TWO_I + 2 * col];
        const float bl = b1[e * TWO_I + 2 * col + 1];
        #pragma unroll
        for (int mi = 0; mi < 4; ++mi) {
            const f32x4 vg = acc[mi][ni];
            const f32x4 vl = acc[mi][ni + 2];
            #pragma unroll
            for (int r = 0; r < 4; ++r) {
                if (ent[mi][r] >= 0) {
                    const float xg = fminf(vg[r] + bg, LIMIT);
                    const float xl = fminf(fmaxf(vl[r] + bl, -LIMIT), LIMIT);
                    const float s = 1.f / (1.f + __expf(-ALPHA * xg));
                    h1[(size_t)ent[mi][r] * IDIM + col] = f2bf(xg * s * (xl + 1.f));
                }
            }
        }
    }
}

// ---------------------------------------------------------------------------
// GEMM2: gathered h1 rows x W2[e]^T + bias, * route weight -> contrib
// Same counted-vmcnt pipeline.
// ---------------------------------------------------------------------------
__global__ __launch_bounds__(256) void k_gemm2(
    const ushort* __restrict__ h1, const ushort* __restrict__ w2bf,
    const float* __restrict__ b2, const float* __restrict__ route_w,
    const int* __restrict__ counts, const int* __restrict__ bucket,
    float* __restrict__ contrib, int n_tok, int rt_max)
{
    const int bx = blockIdx.x;
    const int rt = bx >> 6;
    const int e  = (bx >> 3) & 7;
    const int ct = bx & 7;
    const int cnt = counts[e];
    if (rt * BM >= cnt) return;
    const int c0 = ct * BN;

    __shared__ __align__(16) ushort As[2][BM * BK];
    __shared__ __align__(16) ushort Bs[2][BN * BK];

    const int tid = threadIdx.x;
    const int lane = tid & 63, wid = tid >> 6;
    const int wm = wid >> 1, wn = wid & 1;

    int rowent[4];
    #pragma unroll
    for (int it = 0; it < 4; ++it) {
        int pos = rt * BM + it * 32 + (tid >> 3);
        rowent[it] = bucket[e * n_tok + min(pos, cnt - 1)];
    }
    const ushort* wB = w2bf + (size_t)e * HDIM * IDIM;
    const int swz = (((tid & 7) ^ ((tid >> 3) & 7)) * 8);

    f32x4 acc[4][4];
    #pragma unroll
    for (int mi = 0; mi < 4; ++mi)
        #pragma unroll
        for (int ni = 0; ni < 4; ++ni) acc[mi][ni] = (f32x4)0.f;

    auto stage = [&](int buf, int kt) {
        const int k0 = kt * BK + swz;
        #pragma unroll
        for (int it = 0; it < 4; ++it)
            load_lds16(h1 + (size_t)rowent[it] * IDIM + k0, &As[buf][(it * 32 + wid * 8) * BK]);
        #pragma unroll
        for (int it = 0; it < 4; ++it)
            load_lds16(wB + (size_t)(c0 + it * 32 + (tid >> 3)) * IDIM + k0, &Bs[buf][(it * 32 + wid * 8) * BK]);
    };
    auto compute = [&](int buf) {
        #pragma unroll
        for (int kk = 0; kk < 2; ++kk) {
            bf16x8 a[4], b[4];
            #pragma unroll
            for (int mi = 0; mi < 4; ++mi) {
                int r = wm * 64 + mi * 16 + (lane & 15);
                int off = r * BK + (((kk * 4 + (lane >> 4)) ^ (lane & 7)) * 8);
                a[mi] = *reinterpret_cast<const bf16x8*>(&As[buf][off]);
            }
            #pragma unroll
            for (int ni = 0; ni < 4; ++ni) {
                int r = wn * 64 + ni * 16 + (lane & 15);
                int off = r * BK + (((kk * 4 + (lane >> 4)) ^ (lane & 7)) * 8);
                b[ni] = *reinterpret_cast<const bf16x8*>(&Bs[buf][off]);
            }
            #pragma unroll
            for (int mi = 0; mi < 4; ++mi)
                #pragma unroll
                for (int ni = 0; ni < 4; ++ni)
                    acc[mi][ni] = __builtin_amdgcn_mfma_f32_16x16x32_bf16(a[mi], b[ni], acc[mi][ni], 0, 0, 0);
        }
    };

    stage(0, 0);
    int cur = 0;
    for (int kt = 0; kt < IDIM / BK - 1; ++kt) {
        stage(cur ^ 1, kt + 1);
        WAIT_VM8();
        BAR();
        compute(cur);
        BAR();
        cur ^= 1;
    }
    WAIT_VM0();
    BAR();
    compute(cur);

    int ent[4][4];
    float wgt[4][4];
    #pragma unroll
    for (int mi = 0; mi < 4; ++mi)
        #pragma unroll
        for (int r = 0; r < 4; ++r) {
            int pos = rt * BM + wm * 64 + mi * 16 + (lane >> 4) * 4 + r;
            if (pos < cnt) {
                ent[mi][r] = bucket[e * n_tok + pos];
                wgt[mi][r] = route_w[ent[mi][r]];
            } else ent[mi][r] = -1;
        }
    #pragma unroll
    for (int ni = 0; ni < 4; ++ni) {
        const int c = c0 + wn * 64 + ni * 16 + (lane & 15);
        const float bc = b2[e * HDIM + c];
        #pragma unroll
        for (int mi = 0; mi < 4; ++mi) {
            const f32x4 v = acc[mi][ni];
            #pragma unroll
            for (int r = 0; r < 4; ++r) {
                if (ent[mi][r] >= 0) {
                    const int tok = ent[mi][r] >> 1, slot = ent[mi][r] & 1;
                    contrib[((size_t)slot * n_tok + tok) * HDIM + c] = wgt[mi][r] * (v[r] + bc);
                }
            }
        }
    }
}

// ---------------------------------------------------------------------------
// out = x + contrib[0] + contrib[1]
// ---------------------------------------------------------------------------
__global__ __launch_bounds__(256) void k_combine(
    const float* __restrict__ x, const float* __restrict__ contrib,
    float* __restrict__ out, int n4, int slot_stride4)
{
    int i = blockIdx.x * blockDim.x + threadIdx.x;
    if (i >= n4) return;
    float4 xv = reinterpret_cast<const float4*>(x)[i];
    float4 c0 = reinterpret_cast<const float4*>(contrib)[i];
    float4 c1 = reinterpret_cast<const float4*>(contrib)[i + slot_stride4];
    float4 o;
    o.x = xv.x + c0.x + c1.x;
    o.y = xv.y + c0.y + c1.y;
    o.z = xv.z + c0.z + c1.z;
    o.w = xv.w + c0.w + c1.w;
    reinterpret_cast<float4*>(out)[i] = o;
}

// ---------------------------------------------------------------------------
extern "C" void kernel_launch(void* const* d_in, const int* in_sizes, int n_in,
                              void* d_out, int out_size, void* d_ws, size_t ws_size,
                              hipStream_t stream) {
    const float* x    = (const float*)d_in[0];
    const float* nsc  = (const float*)d_in[1];
    const float* gw   = (const float*)d_in[2];
    const float* gb   = (const float*)d_in[3];
    const float* w1   = (const float*)d_in[4];
    const float* b1   = (const float*)d_in[5];
    const float* w2   = (const float*)d_in[6];
    const float* b2   = (const float*)d_in[7];
    float* out = (float*)d_out;

    const int N = in_sizes[0] / HDIM;
    const int rt_max = (N + BM - 1) / BM;

    uintptr_t p = (uintptr_t)d_ws;
    auto carve = [&p](size_t bytes) { uintptr_t q = p; p += (bytes + 255) & ~(size_t)255; return q; };
    ushort* t_bf    = (ushort*)carve((size_t)N * HDIM * 2);
    ushort* w1bf    = (ushort*)carve((size_t)NEXP * TWO_I * HDIM * 2);
    ushort* w2bf    = (ushort*)carve((size_t)NEXP * HDIM * IDIM * 2);
    ushort* h1      = (ushort*)carve((size_t)N * TOPK * IDIM * 2);
    float*  contrib = (float*)carve((size_t)TOPK * N * HDIM * 4);
    float*  route_w = (float*)carve((size_t)N * TOPK * 4);
    int*    bucket  = (int*)carve((size_t)NEXP * N * 4);
    int*    eidx    = (int*)carve((size_t)N * TOPK * 4);
    int*    counts  = (int*)carve(256);

    hipMemsetAsync(counts, 0, NEXP * sizeof(int), stream);

    // weight conversion
    k_conv_w1<<<NEXP * TWO_I, 256, 0, stream>>>(w1, w1bf);
    const int n4w2 = NEXP * HDIM * IDIM / 4;
    k_f32_to_bf16<<<2048, 256, 0, stream>>>(w2, w2bf, n4w2);

    // rmsnorm + gate (wave per token), then ballot-based bucket build
    k_norm_gate<<<(N + 3) / 4, 256, 0, stream>>>(x, nsc, gw, gb, t_bf, route_w, eidx, N);
    k_bucket<<<BKT_BLOCKS, 256, 0, stream>>>(eidx, counts, bucket, N);

    // expert GEMMs (rt slowest -> active blocks contiguous)
    k_gemm1<<<rt_max * NEXP * (TWO_I / BN), 256, 0, stream>>>(t_bf, w1bf, b1, counts, bucket, h1, N, rt_max);
    k_gemm2<<<rt_max * NEXP * (HDIM / BN), 256, 0, stream>>>(h1, w2bf, b2, route_w, counts, bucket, contrib, N, rt_max);

    // combine + residual
    const int n4 = N * HDIM / 4;
    k_combine<<<(n4 + 255) / 256, 256, 0, stream>>>(x, contrib, out, n4, n4);
}